// Round 7
// baseline (344.830 us; speedup 1.0000x reference)
//
#include <hip/hip_runtime.h>

#define NN 384
#define NF 512
#define NH 192
#define NC 64

typedef __bf16 bf16x8 __attribute__((ext_vector_type(8)));
typedef float f32x4 __attribute__((ext_vector_type(4)));

static __device__ __forceinline__ float b2f(unsigned short u) {
  union { unsigned int i; float f; } v; v.i = ((unsigned int)u) << 16; return v.f;
}
static __device__ __forceinline__ unsigned short f2b(float f) {
  unsigned int u = __float_as_uint(f);
  unsigned int r = (u + 0x7FFFu + ((u >> 16) & 1u)) >> 16;
  return (unsigned short)r;
}

// A: x_init = x@W_emb + b_emb ; t1 = x_init@W1 ; uT = bf16(x_init)^T
__global__ void __launch_bounds__(192) k_emb(
    const float* __restrict__ x, const float* __restrict__ W_emb,
    const float* __restrict__ b_emb, const float* __restrict__ W1,
    float* __restrict__ xinit, float* __restrict__ t1,
    unsigned short* __restrict__ uT)
{
  __shared__ float xl[4][NF];
  __shared__ float xi[4][NH];
  const int r0 = blockIdx.x * 4;
  const int tid = threadIdx.x;
#pragma unroll
  for (int rr = 0; rr < 4; ++rr)
    for (int k = tid; k < NF; k += 192)
      xl[rr][k] = x[(size_t)(r0 + rr) * NF + k];
  __syncthreads();
  const int h = tid;
  float a0 = b_emb[h], a1 = a0, a2 = a0, a3 = a0;
  for (int k = 0; k < NF; ++k) {
    float w = W_emb[k * NH + h];
    a0 += xl[0][k] * w; a1 += xl[1][k] * w; a2 += xl[2][k] * w; a3 += xl[3][k] * w;
  }
  float acc[4] = {a0, a1, a2, a3};
#pragma unroll
  for (int rr = 0; rr < 4; ++rr) {
    xinit[(r0 + rr) * NH + h] = acc[rr];
    xi[rr][h] = acc[rr];
    uT[h * NN + (r0 + rr)] = f2b(acc[rr]);
  }
  __syncthreads();
  float c0 = 0.f, c1 = 0.f, c2 = 0.f, c3 = 0.f;
  for (int k = 0; k < NH; ++k) {
    float w = W1[k * NH + h];
    c0 += xi[0][k] * w; c1 += xi[1][k] * w; c2 += xi[2][k] * w; c3 += xi[3][k] * w;
  }
  t1[(r0 + 0) * NH + h] = c0;
  t1[(r0 + 1) * NH + h] = c1;
  t1[(r0 + 2) * NH + h] = c2;
  t1[(r0 + 3) * NH + h] = c3;
}

// C: x1 = relu(adj@t1 + b1) ; vT = bf16(x1)^T
__global__ void __launch_bounds__(192) k_gc1(
    const float* __restrict__ adj, const float* __restrict__ t1,
    const float* __restrict__ b1, float* __restrict__ x1,
    unsigned short* __restrict__ vT)
{
  __shared__ float al[4][NN];
  const int r0 = blockIdx.x * 4;
  const int tid = threadIdx.x;
#pragma unroll
  for (int rr = 0; rr < 4; ++rr)
    for (int j = tid; j < NN; j += 192)
      al[rr][j] = adj[(size_t)(r0 + rr) * NN + j];
  __syncthreads();
  const int h = tid;
  float a0 = b1[h], a1 = a0, a2 = a0, a3 = a0;
  for (int j = 0; j < NN; ++j) {
    float t = t1[j * NH + h];
    a0 += al[0][j] * t; a1 += al[1][j] * t; a2 += al[2][j] * t; a3 += al[3][j] * t;
  }
  float acc[4] = {a0, a1, a2, a3};
#pragma unroll
  for (int rr = 0; rr < 4; ++rr) {
    float v = fmaxf(acc[rr], 0.f);
    x1[(r0 + rr) * NH + h] = v;
    vT[h * NN + (r0 + rr)] = f2b(v);
  }
}

// D: E0 = adj1 @ outer(u,u), E1 = adj1 @ outer(v,v). OPERAND-SWAPPED MFMA:
// compute M^T = U^T * A_r^T, so adj1 rows feed the B-operand DIRECTLY from
// global->registers (8 consecutive floats per lane) -- no LDS, no barriers,
// no swizzle in the main loop. grid 1152 = 384 r x 3 ig (128 i-rows).
// Block 512 = 8 independent waves (rg4 x uv2): wave owns i-rows
// [ig*128+rg*32, +32) (2 i-tiles), ALL 12 h-tiles, full K, one of {u|v}.
// A ping-pong (depth-1 prefetch, 32KB in flight/CU); uf tiles JIT from L2.
// Single __syncthreads at the end for the rg-reduction.
__global__ void __launch_bounds__(512) k_edge(
    const float* __restrict__ adj1, const unsigned short* __restrict__ uT,
    const unsigned short* __restrict__ vT,
    float* __restrict__ E0p, float* __restrict__ E1p)
{
  __shared__ float red[2][4][NH];   // [uv][rg][h]

  const int tid = threadIdx.x;
  const int wv = tid >> 6, l = tid & 63;
  const int lr = l & 15, lg = l >> 4;
  const int rg = wv >> 1, uv = wv & 1;
  const int r = blockIdx.x / 3, ig = blockIdx.x - r * 3;
  const int i0w = ig * 128 + rg * 32;
  const float* __restrict__ Ar = adj1 + (size_t)r * (NN * NN);
  const unsigned short* __restrict__ selT = uv ? vT : uT;

  // B-operand sources: native A_r rows. lane (lr,lg) reads
  // A_r[i0w + s2*16 + lr][kb + lg*8 .. +8]  (32B contiguous per lane)
  const float* arow0 = Ar + (size_t)(i0w + lr) * NN + lg * 8;
  const float* arow1 = Ar + (size_t)(i0w + 16 + lr) * NN + lg * 8;

  f32x4 acc[12][2];
  const f32x4 zero = {0.f, 0.f, 0.f, 0.f};
#pragma unroll
  for (int mt = 0; mt < 12; ++mt) { acc[mt][0] = zero; acc[mt][1] = zero; }

  f32x4 A[2][2][2];  // [set][s2][quad] -- set index static under full unroll

#define LOAD_A(set, kb)                                                        \
  {                                                                            \
    A[set][0][0] = *reinterpret_cast<const f32x4*>(arow0 + (kb));              \
    A[set][0][1] = *reinterpret_cast<const f32x4*>(arow0 + (kb) + 4);          \
    A[set][1][0] = *reinterpret_cast<const f32x4*>(arow1 + (kb));              \
    A[set][1][1] = *reinterpret_cast<const f32x4*>(arow1 + (kb) + 4);          \
  }

  LOAD_A(0, 0);

#pragma unroll
  for (int n = 0; n < 12; ++n) {
    const int kb = n * 32;
    const int cur = n & 1;
    if (n < 11) LOAD_A(cur ^ 1, kb + 32);

    // A-operand tiles: uf[mt] = U^T[mt*16+lr][kb+lg*8 .. +8] (16B contiguous)
    bf16x8 uf[12];
#pragma unroll
    for (int mt = 0; mt < 12; ++mt)
      uf[mt] = *reinterpret_cast<const bf16x8*>(selT + (mt * 16 + lr) * NN + kb + lg * 8);

    // convert the two A_r row-fragments to bf16 (B-operand)
    bf16x8 af0, af1;
#pragma unroll
    for (int e = 0; e < 4; ++e) {
      af0[e]     = (__bf16)A[cur][0][0][e];
      af0[e + 4] = (__bf16)A[cur][0][1][e];
      af1[e]     = (__bf16)A[cur][1][0][e];
      af1[e + 4] = (__bf16)A[cur][1][1][e];
    }

#pragma unroll
    for (int mt = 0; mt < 12; ++mt) {
      acc[mt][0] = __builtin_amdgcn_mfma_f32_16x16x32_bf16(uf[mt], af0, acc[mt][0], 0, 0, 0);
      acc[mt][1] = __builtin_amdgcn_mfma_f32_16x16x32_bf16(uf[mt], af1, acc[mt][1], 0, 0, 0);
    }
  }
#undef LOAD_A

  // fold: e[h] = sum_i w[i,h]*M^T[h,i]; acc elem q: h = mt*16+lg*4+q,
  // i = i0w + s2*16 + lr. Then reduce over lr (16 lanes) via shfl.
  float e[12][4];
#pragma unroll
  for (int mt = 0; mt < 12; ++mt) {
#pragma unroll
    for (int q = 0; q < 4; ++q) {
      const int h = mt * 16 + lg * 4 + q;
      float s = b2f(selT[h * NN + i0w + lr]) * acc[mt][0][q]
              + b2f(selT[h * NN + i0w + 16 + lr]) * acc[mt][1][q];
#pragma unroll
      for (int m = 1; m < 16; m <<= 1) s += __shfl_xor(s, m);
      e[mt][q] = s;
    }
  }

  if (lr == 0) {
#pragma unroll
    for (int mt = 0; mt < 12; ++mt)
#pragma unroll
      for (int q = 0; q < 4; ++q)
        red[uv][rg][mt * 16 + lg * 4 + q] = e[mt][q];
  }
  __syncthreads();
  if (tid < 2 * NH) {
    const int uvx = tid / NH, h = tid - uvx * NH;
    float s = red[uvx][0][h] + red[uvx][1][h] + red[uvx][2][h] + red[uvx][3][h];
    float* Ep = uvx ? E1p : E0p;
    Ep[((size_t)ig * NN + r) * NH + h] = s;
  }
}

// E: x_e = relu(E0@We+be); xs = x1+x_e+x_init; t2 = xs@W2; xe2 = (E0+E1)@We2+be2
// NOTE: t2 aliases E0p plane0, xe2 aliases E0p plane1 (reads complete before
// writes within each block; blocks touch disjoint rows).
__global__ void __launch_bounds__(192) k_mid(
    const float* __restrict__ E0p, const float* __restrict__ E1p,
    const float* __restrict__ x1, const float* __restrict__ xinit,
    const float* __restrict__ We, const float* __restrict__ be,
    const float* __restrict__ W2, const float* __restrict__ We2,
    const float* __restrict__ be2, float* __restrict__ t2,
    float* __restrict__ xe2)
{
  __shared__ float e0l[4][NH], s01[4][NH], xsl[4][NH];
  const int r0 = blockIdx.x * 4;
  const int h = threadIdx.x;
#pragma unroll
  for (int rr = 0; rr < 4; ++rr) {
    const int idx = (r0 + rr) * NH + h;
    float e0v = E0p[idx] + E0p[NN * NH + idx] + E0p[2 * NN * NH + idx];
    float e1v = E1p[idx] + E1p[NN * NH + idx] + E1p[2 * NN * NH + idx];
    e0l[rr][h] = e0v;
    s01[rr][h] = e0v + e1v;
  }
  __syncthreads();
  float x0 = be[h], x1a = x0, x2 = x0, x3 = x0;
  for (int k = 0; k < NH; ++k) {
    float w = We[k * NH + h];
    x0 += e0l[0][k] * w; x1a += e0l[1][k] * w; x2 += e0l[2][k] * w; x3 += e0l[3][k] * w;
  }
  float xe[4] = {x0, x1a, x2, x3};
#pragma unroll
  for (int rr = 0; rr < 4; ++rr) {
    const int idx = (r0 + rr) * NH + h;
    xsl[rr][h] = fmaxf(xe[rr], 0.f) + x1[idx] + xinit[idx];
  }
  __syncthreads();
  float t0 = 0.f, t1v = 0.f, t2v = 0.f, t3 = 0.f;
  float b0 = be2[h], b1v = b0, b2v = b0, b3 = b0;
  for (int k = 0; k < NH; ++k) {
    float w2 = W2[k * NH + h];
    float w3 = We2[k * NH + h];
    t0 += xsl[0][k] * w2; t1v += xsl[1][k] * w2; t2v += xsl[2][k] * w2; t3 += xsl[3][k] * w2;
    b0 += s01[0][k] * w3; b1v += s01[1][k] * w3; b2v += s01[2][k] * w3; b3 += s01[3][k] * w3;
  }
  t2[(r0 + 0) * NH + h] = t0;  t2[(r0 + 1) * NH + h] = t1v;
  t2[(r0 + 2) * NH + h] = t2v; t2[(r0 + 3) * NH + h] = t3;
  xe2[(r0 + 0) * NH + h] = b0;  xe2[(r0 + 1) * NH + h] = b1v;
  xe2[(r0 + 2) * NH + h] = b2v; xe2[(r0 + 3) * NH + h] = b3;
}

// F: x_mid = adj@t2 + b2; h = relu(x_mid + xe2); logits = h@W_cls + b_cls; log_softmax
__global__ void __launch_bounds__(256) k_out(
    const float* __restrict__ adj, const float* __restrict__ t2,
    const float* __restrict__ b2, const float* __restrict__ xe2,
    const float* __restrict__ Wc, const float* __restrict__ bc,
    float* __restrict__ out)
{
  __shared__ float al[4][NN];
  __shared__ float hl[4][NH];
  const int r0 = blockIdx.x * 4;
  const int tid = threadIdx.x;
#pragma unroll
  for (int rr = 0; rr < 4; ++rr)
    for (int j = tid; j < NN; j += 256)
      al[rr][j] = adj[(size_t)(r0 + rr) * NN + j];
  __syncthreads();
  if (tid < NH) {
    const int h = tid;
    float a0 = b2[h], a1 = a0, a2 = a0, a3 = a0;
    for (int j = 0; j < NN; ++j) {
      float t = t2[j * NH + h];
      a0 += al[0][j] * t; a1 += al[1][j] * t; a2 += al[2][j] * t; a3 += al[3][j] * t;
    }
    float acc[4] = {a0, a1, a2, a3};
#pragma unroll
    for (int rr = 0; rr < 4; ++rr)
      hl[rr][h] = fmaxf(acc[rr] + xe2[(r0 + rr) * NH + h], 0.f);
  }
  __syncthreads();
  const int w = tid >> 6, lane = tid & 63;
  float lgt = bc[lane];
  for (int k = 0; k < NH; ++k) lgt += hl[w][k] * Wc[k * NC + lane];
  float m = lgt;
#pragma unroll
  for (int off = 32; off >= 1; off >>= 1) m = fmaxf(m, __shfl_xor(m, off));
  float s = expf(lgt - m);
#pragma unroll
  for (int off = 32; off >= 1; off >>= 1) s += __shfl_xor(s, off);
  out[(size_t)(r0 + w) * NC + lane] = lgt - m - logf(s);
}

extern "C" void kernel_launch(void* const* d_in, const int* in_sizes, int n_in,
                              void* d_out, int out_size, void* d_ws, size_t ws_size,
                              hipStream_t stream) {
  const float* x     = (const float*)d_in[0];
  const float* adj   = (const float*)d_in[1];
  const float* adj1  = (const float*)d_in[2];
  const float* W_emb = (const float*)d_in[3];
  const float* b_emb = (const float*)d_in[4];
  const float* W_cls = (const float*)d_in[5];
  const float* b_cls = (const float*)d_in[6];
  const float* W1    = (const float*)d_in[7];
  const float* b1    = (const float*)d_in[8];
  const float* W2    = (const float*)d_in[9];
  const float* b2    = (const float*)d_in[10];
  const float* We    = (const float*)d_in[11];
  const float* be    = (const float*)d_in[12];
  const float* We2   = (const float*)d_in[13];
  const float* be2   = (const float*)d_in[14];

  // ws layout (total 2,949,120 B -- identical to the proven footprint)
  char* ws = (char*)d_ws;
  float* xinit = (float*)(ws + 0);
  float* t1    = (float*)(ws + 294912);
  float* x1    = (float*)(ws + 589824);
  float* E0p   = (float*)(ws + 884736);      // [3][384*192] f32
  float* E1p   = (float*)(ws + 1769472);     // [3][384*192] f32
  unsigned short* uT = (unsigned short*)(ws + 2654208);  // [192][384] bf16
  unsigned short* vT = (unsigned short*)(ws + 2801664);  // [192][384] bf16
  // t2/xe2 alias E0p planes 0/1 (k_mid reads before writing; rows disjoint per block)
  float* t2  = E0p;
  float* xe2 = E0p + NN * NH;

  k_emb<<<96, 192, 0, stream>>>(x, W_emb, b_emb, W1, xinit, t1, uT);
  k_gc1<<<96, 192, 0, stream>>>(adj, t1, b1, x1, vT);
  k_edge<<<1152, 512, 0, stream>>>(adj1, uT, vT, E0p, E1p);
  k_mid<<<96, 192, 0, stream>>>(E0p, E1p, x1, xinit, We, be, W2, We2, be2, t2, xe2);
  k_out<<<96, 256, 0, stream>>>(adj, t2, b2, xe2, W_cls, b_cls, (float*)d_out);
}

// Round 8
// 290.154 us; speedup vs baseline: 1.1884x; 1.1884x over previous
//
#include <hip/hip_runtime.h>

#define NN 384
#define NF 512
#define NH 192
#define NC 64

typedef __bf16 bf16x8 __attribute__((ext_vector_type(8)));
typedef float f32x4 __attribute__((ext_vector_type(4)));

static __device__ __forceinline__ float b2f(unsigned short u) {
  union { unsigned int i; float f; } v; v.i = ((unsigned int)u) << 16; return v.f;
}
static __device__ __forceinline__ unsigned short f2b(float f) {
  unsigned int u = __float_as_uint(f);
  unsigned int r = (u + 0x7FFFu + ((u >> 16) & 1u)) >> 16;
  return (unsigned short)r;
}

// A: x_init = x@W_emb + b_emb ; t1 = x_init@W1 ; uT = bf16(x_init)^T ;
//    Upk = MFMA-B-frag-packed bf16 x_init: Upk[(r>>3)*1536 + h*8 + (r&7)]
__global__ void __launch_bounds__(192) k_emb(
    const float* __restrict__ x, const float* __restrict__ W_emb,
    const float* __restrict__ b_emb, const float* __restrict__ W1,
    float* __restrict__ xinit, float* __restrict__ t1,
    unsigned short* __restrict__ uT, unsigned short* __restrict__ Upk)
{
  __shared__ float xl[4][NF];
  __shared__ float xi[4][NH];
  const int r0 = blockIdx.x * 4;
  const int tid = threadIdx.x;
#pragma unroll
  for (int rr = 0; rr < 4; ++rr)
    for (int k = tid; k < NF; k += 192)
      xl[rr][k] = x[(size_t)(r0 + rr) * NF + k];
  __syncthreads();
  const int h = tid;
  float a0 = b_emb[h], a1 = a0, a2 = a0, a3 = a0;
  for (int k = 0; k < NF; ++k) {
    float w = W_emb[k * NH + h];
    a0 += xl[0][k] * w; a1 += xl[1][k] * w; a2 += xl[2][k] * w; a3 += xl[3][k] * w;
  }
  float acc[4] = {a0, a1, a2, a3};
  ushort4 pk;
  pk.x = f2b(acc[0]); pk.y = f2b(acc[1]); pk.z = f2b(acc[2]); pk.w = f2b(acc[3]);
  *reinterpret_cast<ushort4*>(Upk + (r0 >> 3) * 1536 + h * 8 + (r0 & 7)) = pk;
#pragma unroll
  for (int rr = 0; rr < 4; ++rr) {
    xinit[(r0 + rr) * NH + h] = acc[rr];
    xi[rr][h] = acc[rr];
    uT[h * NN + (r0 + rr)] = f2b(acc[rr]);
  }
  __syncthreads();
  float c0 = 0.f, c1 = 0.f, c2 = 0.f, c3 = 0.f;
  for (int k = 0; k < NH; ++k) {
    float w = W1[k * NH + h];
    c0 += xi[0][k] * w; c1 += xi[1][k] * w; c2 += xi[2][k] * w; c3 += xi[3][k] * w;
  }
  t1[(r0 + 0) * NH + h] = c0;
  t1[(r0 + 1) * NH + h] = c1;
  t1[(r0 + 2) * NH + h] = c2;
  t1[(r0 + 3) * NH + h] = c3;
}

// C: x1 = relu(adj@t1 + b1) ; vT = bf16(x1)^T ; Vpk packed like Upk
__global__ void __launch_bounds__(192) k_gc1(
    const float* __restrict__ adj, const float* __restrict__ t1,
    const float* __restrict__ b1, float* __restrict__ x1,
    unsigned short* __restrict__ vT, unsigned short* __restrict__ Vpk)
{
  __shared__ float al[4][NN];
  const int r0 = blockIdx.x * 4;
  const int tid = threadIdx.x;
#pragma unroll
  for (int rr = 0; rr < 4; ++rr)
    for (int j = tid; j < NN; j += 192)
      al[rr][j] = adj[(size_t)(r0 + rr) * NN + j];
  __syncthreads();
  const int h = tid;
  float a0 = b1[h], a1 = a0, a2 = a0, a3 = a0;
  for (int j = 0; j < NN; ++j) {
    float t = t1[j * NH + h];
    a0 += al[0][j] * t; a1 += al[1][j] * t; a2 += al[2][j] * t; a3 += al[3][j] * t;
  }
  float acc[4] = {a0, a1, a2, a3};
  float v0 = fmaxf(acc[0], 0.f), v1 = fmaxf(acc[1], 0.f);
  float v2 = fmaxf(acc[2], 0.f), v3 = fmaxf(acc[3], 0.f);
  ushort4 pk;
  pk.x = f2b(v0); pk.y = f2b(v1); pk.z = f2b(v2); pk.w = f2b(v3);
  *reinterpret_cast<ushort4*>(Vpk + (r0 >> 3) * 1536 + h * 8 + (r0 & 7)) = pk;
  float vv[4] = {v0, v1, v2, v3};
#pragma unroll
  for (int rr = 0; rr < 4; ++rr) {
    x1[(r0 + rr) * NH + h] = vv[rr];
    vT[h * NN + (r0 + rr)] = pk.x;  // placeholder overwritten below
  }
  vT[h * NN + (r0 + 0)] = pk.x;
  vT[h * NN + (r0 + 1)] = pk.y;
  vT[h * NN + (r0 + 2)] = pk.z;
  vT[h * NN + (r0 + 3)] = pk.w;
}

// D: E0 = adj1 @ outer(u,u), E1 = adj1 @ outer(v,v). Single HBM pass.
// grid 768 = 384 r x 2 ihalf (192 i-rows). Block 512 = 8 waves (hg4 x uv2):
// wave owns 48 h x {u|v} x all 192 i (3 rounds of 64). R4's 2-barrier dbuf
// skeleton with: A reg-staged as BF16 (1 ds_read_b128 per af, cvt out of the
// inner loop, T14 issue-early/write-late), B fragments from global in exact
// MFMA order (Upk/Vpk, ring-2 in registers, no LDS B, no bank conflicts),
// LDS 16KB + acc 48 VGPR -> 2 blocks/CU so barrier drains overlap.
__global__ void __launch_bounds__(512, 4) k_edge(
    const float* __restrict__ adj1,
    const unsigned short* __restrict__ uT, const unsigned short* __restrict__ vT,
    const unsigned short* __restrict__ Upk, const unsigned short* __restrict__ Vpk,
    float* __restrict__ E0p, float* __restrict__ E1p)
{
  __shared__ __align__(16) unsigned short Ab[2][4096];  // 2 x (64 rows x 64 k) bf16

  const int tid = threadIdx.x;
  const int wv = tid >> 6, l = tid & 63;
  const int lr = l & 15, lg = l >> 4;
  const int hg = wv >> 1, uv = wv & 1;
  const int r = blockIdx.x >> 1, ih = blockIdx.x & 1;
  const float* __restrict__ Ar = adj1 + (size_t)r * (NN * NN);
  const unsigned short* __restrict__ selT = uv ? vT : uT;
  const unsigned short* __restrict__ selP = uv ? Vpk : Upk;

  // stage mapping: thread -> (row SR, 8-k unit SU); swizzled LDS ush offset
  const int SR = tid >> 3;
  const int SU = tid & 7;
  const int SW = SR * 64 + ((SU ^ (SR & 7)) * 8);

  // B-frag lane offsets (ush): frag(t, n32) at selP + n32*6144 + hoff[t]
  int hoff[3];
#pragma unroll
  for (int t = 0; t < 3; ++t)
    hoff[t] = lg * 1536 + ((hg * 3 + t) * 16 + lr) * 8;

  // A-read lds offsets per (s, kh)
  // af(s,kh) at Ab[buf][(s*16+lr)*64 + (((kh*4+lg)^(lr&7))*8)]
  int aoff[4][2];
#pragma unroll
  for (int s = 0; s < 4; ++s)
#pragma unroll
    for (int kh = 0; kh < 2; ++kh)
      aoff[s][kh] = (s * 16 + lr) * 64 + (((kh * 4 + lg) ^ (lr & 7)) * 8);

  bf16x8 bcur[3][2], bnxt[3][2];
  f32x4 acc[4][3];
  const f32x4 zero = {0.f, 0.f, 0.f, 0.f};
  float e[3] = {0.f, 0.f, 0.f};
#pragma unroll
  for (int s = 0; s < 4; ++s)
#pragma unroll
    for (int t = 0; t < 3; ++t) acc[s][t] = zero;

  // prologue: stage A(0), load B(0)
  {
    const float* gp = Ar + (size_t)(ih * 192 + SR) * NN + SU * 8;
    f32x4 q0 = *reinterpret_cast<const f32x4*>(gp);
    f32x4 q1 = *reinterpret_cast<const f32x4*>(gp + 4);
    bf16x8 an;
#pragma unroll
    for (int ee = 0; ee < 4; ++ee) { an[ee] = (__bf16)q0[ee]; an[ee + 4] = (__bf16)q1[ee]; }
    *reinterpret_cast<bf16x8*>(&Ab[0][SW]) = an;
#pragma unroll
    for (int t = 0; t < 3; ++t)
#pragma unroll
      for (int kh = 0; kh < 2; ++kh)
        bcur[t][kh] = *reinterpret_cast<const bf16x8*>(selP + kh * 6144 + hoff[t]);
  }
  __syncthreads();

#pragma unroll
  for (int g = 0; g < 18; ++g) {
    const int ri = g / 6, kc = g % 6;
    f32x4 q0n, q1n;
    if (g < 17) {
      const int gn = g + 1;
      const int i0n = ih * 192 + (gn / 6) * 64;
      const int kbn = (gn % 6) * 64;
      const float* gp = Ar + (size_t)(i0n + SR) * NN + kbn + SU * 8;
      q0n = *reinterpret_cast<const f32x4*>(gp);
      q1n = *reinterpret_cast<const f32x4*>(gp + 4);
      const int n32b = (gn % 6) * 2;
#pragma unroll
      for (int t = 0; t < 3; ++t)
#pragma unroll
        for (int kh = 0; kh < 2; ++kh)
          bnxt[t][kh] = *reinterpret_cast<const bf16x8*>(selP + (n32b + kh) * 6144 + hoff[t]);
    }

    // compute chunk g from Ab[g&1] + bcur
#pragma unroll
    for (int s = 0; s < 4; ++s) {
#pragma unroll
      for (int kh = 0; kh < 2; ++kh) {
        bf16x8 af = *reinterpret_cast<const bf16x8*>(&Ab[g & 1][aoff[s][kh]]);
#pragma unroll
        for (int t = 0; t < 3; ++t)
          acc[s][t] = __builtin_amdgcn_mfma_f32_16x16x32_bf16(af, bcur[t][kh], acc[s][t], 0, 0, 0);
      }
    }

    // end of round: fold acc into e (R4-verified mapping), reset acc
    if (kc == 5) {
      const int i0 = ih * 192 + ri * 64;
#pragma unroll
      for (int t = 0; t < 3; ++t) {
        const int h = (hg * 3 + t) * 16 + lr;
#pragma unroll
        for (int s = 0; s < 4; ++s) {
          const int ii = i0 + s * 16 + lg * 4;
          ushort4 w4 = *reinterpret_cast<const ushort4*>(selT + h * NN + ii);
          e[t] += b2f(w4.x) * acc[s][t][0] + b2f(w4.y) * acc[s][t][1]
                + b2f(w4.z) * acc[s][t][2] + b2f(w4.w) * acc[s][t][3];
        }
      }
#pragma unroll
      for (int s = 0; s < 4; ++s)
#pragma unroll
        for (int t = 0; t < 3; ++t) acc[s][t] = zero;
    }

    // write-late: stage A(g+1) into other buffer (compiler waits on q0n/q1n)
    if (g < 17) {
      bf16x8 an;
#pragma unroll
      for (int ee = 0; ee < 4; ++ee) { an[ee] = (__bf16)q0n[ee]; an[ee + 4] = (__bf16)q1n[ee]; }
      *reinterpret_cast<bf16x8*>(&Ab[(g + 1) & 1][SW]) = an;
    }
    __syncthreads();
#pragma unroll
    for (int t = 0; t < 3; ++t)
#pragma unroll
      for (int kh = 0; kh < 2; ++kh) bcur[t][kh] = bnxt[t][kh];
  }

  // reduce over lg groups (i-subsets within wave); write E-partial plane ih
#pragma unroll
  for (int t = 0; t < 3; ++t) {
    e[t] += __shfl_xor(e[t], 16);
    e[t] += __shfl_xor(e[t], 32);
  }
  if (lg == 0) {
    float* Ep = uv ? E1p : E0p;
#pragma unroll
    for (int t = 0; t < 3; ++t) {
      const int h = (hg * 3 + t) * 16 + lr;
      Ep[((size_t)ih * NN + r) * NH + h] = e[t];
    }
  }
}

// E: x_e = relu(E0@We+be); xs = x1+x_e+x_init; t2 = xs@W2; xe2 = (E0+E1)@We2+be2
// NOTE: t2 aliases E0p plane0, xe2 aliases E0p plane1 (reads complete before
// writes within each block; blocks touch disjoint rows).
__global__ void __launch_bounds__(192) k_mid(
    const float* __restrict__ E0p, const float* __restrict__ E1p,
    const float* __restrict__ x1, const float* __restrict__ xinit,
    const float* __restrict__ We, const float* __restrict__ be,
    const float* __restrict__ W2, const float* __restrict__ We2,
    const float* __restrict__ be2, float* __restrict__ t2,
    float* __restrict__ xe2)
{
  __shared__ float e0l[4][NH], s01[4][NH], xsl[4][NH];
  const int r0 = blockIdx.x * 4;
  const int h = threadIdx.x;
#pragma unroll
  for (int rr = 0; rr < 4; ++rr) {
    const int idx = (r0 + rr) * NH + h;
    float e0v = E0p[idx] + E0p[NN * NH + idx];
    float e1v = E1p[idx] + E1p[NN * NH + idx];
    e0l[rr][h] = e0v;
    s01[rr][h] = e0v + e1v;
  }
  __syncthreads();
  float x0 = be[h], x1a = x0, x2 = x0, x3 = x0;
  for (int k = 0; k < NH; ++k) {
    float w = We[k * NH + h];
    x0 += e0l[0][k] * w; x1a += e0l[1][k] * w; x2 += e0l[2][k] * w; x3 += e0l[3][k] * w;
  }
  float xe[4] = {x0, x1a, x2, x3};
#pragma unroll
  for (int rr = 0; rr < 4; ++rr) {
    const int idx = (r0 + rr) * NH + h;
    xsl[rr][h] = fmaxf(xe[rr], 0.f) + x1[idx] + xinit[idx];
  }
  __syncthreads();
  float t0 = 0.f, t1v = 0.f, t2v = 0.f, t3 = 0.f;
  float b0 = be2[h], b1v = b0, b2v = b0, b3 = b0;
  for (int k = 0; k < NH; ++k) {
    float w2 = W2[k * NH + h];
    float w3 = We2[k * NH + h];
    t0 += xsl[0][k] * w2; t1v += xsl[1][k] * w2; t2v += xsl[2][k] * w2; t3 += xsl[3][k] * w2;
    b0 += s01[0][k] * w3; b1v += s01[1][k] * w3; b2v += s01[2][k] * w3; b3 += s01[3][k] * w3;
  }
  t2[(r0 + 0) * NH + h] = t0;  t2[(r0 + 1) * NH + h] = t1v;
  t2[(r0 + 2) * NH + h] = t2v; t2[(r0 + 3) * NH + h] = t3;
  xe2[(r0 + 0) * NH + h] = b0;  xe2[(r0 + 1) * NH + h] = b1v;
  xe2[(r0 + 2) * NH + h] = b2v; xe2[(r0 + 3) * NH + h] = b3;
}

// F: x_mid = adj@t2 + b2; h = relu(x_mid + xe2); logits = h@W_cls + b_cls; log_softmax
__global__ void __launch_bounds__(256) k_out(
    const float* __restrict__ adj, const float* __restrict__ t2,
    const float* __restrict__ b2, const float* __restrict__ xe2,
    const float* __restrict__ Wc, const float* __restrict__ bc,
    float* __restrict__ out)
{
  __shared__ float al[4][NN];
  __shared__ float hl[4][NH];
  const int r0 = blockIdx.x * 4;
  const int tid = threadIdx.x;
#pragma unroll
  for (int rr = 0; rr < 4; ++rr)
    for (int j = tid; j < NN; j += 256)
      al[rr][j] = adj[(size_t)(r0 + rr) * NN + j];
  __syncthreads();
  if (tid < NH) {
    const int h = tid;
    float a0 = b2[h], a1 = a0, a2 = a0, a3 = a0;
    for (int j = 0; j < NN; ++j) {
      float t = t2[j * NH + h];
      a0 += al[0][j] * t; a1 += al[1][j] * t; a2 += al[2][j] * t; a3 += al[3][j] * t;
    }
    float acc[4] = {a0, a1, a2, a3};
#pragma unroll
    for (int rr = 0; rr < 4; ++rr)
      hl[rr][h] = fmaxf(acc[rr] + xe2[(r0 + rr) * NH + h], 0.f);
  }
  __syncthreads();
  const int w = tid >> 6, lane = tid & 63;
  float lgt = bc[lane];
  for (int k = 0; k < NH; ++k) lgt += hl[w][k] * Wc[k * NC + lane];
  float m = lgt;
#pragma unroll
  for (int off = 32; off >= 1; off >>= 1) m = fmaxf(m, __shfl_xor(m, off));
  float s = expf(lgt - m);
#pragma unroll
  for (int off = 32; off >= 1; off >>= 1) s += __shfl_xor(s, off);
  out[(size_t)(r0 + w) * NC + lane] = lgt - m - logf(s);
}

extern "C" void kernel_launch(void* const* d_in, const int* in_sizes, int n_in,
                              void* d_out, int out_size, void* d_ws, size_t ws_size,
                              hipStream_t stream) {
  const float* x     = (const float*)d_in[0];
  const float* adj   = (const float*)d_in[1];
  const float* adj1  = (const float*)d_in[2];
  const float* W_emb = (const float*)d_in[3];
  const float* b_emb = (const float*)d_in[4];
  const float* W_cls = (const float*)d_in[5];
  const float* b_cls = (const float*)d_in[6];
  const float* W1    = (const float*)d_in[7];
  const float* b1    = (const float*)d_in[8];
  const float* W2    = (const float*)d_in[9];
  const float* b2    = (const float*)d_in[10];
  const float* We    = (const float*)d_in[11];
  const float* be    = (const float*)d_in[12];
  const float* We2   = (const float*)d_in[13];
  const float* be2   = (const float*)d_in[14];

  // ws layout (total 2,654,208 B -- under the proven 2,949,120 footprint)
  char* ws = (char*)d_ws;
  float* xinit = (float*)(ws + 0);           // 294912
  float* t1    = (float*)(ws + 294912);      // 294912
  float* x1    = (float*)(ws + 589824);      // 294912
  float* E0p   = (float*)(ws + 884736);      // [2][384*192] f32 = 589824
  float* E1p   = (float*)(ws + 1474560);     // [2][384*192] f32 = 589824
  unsigned short* Upk = (unsigned short*)(ws + 2064384);  // 147456
  unsigned short* Vpk = (unsigned short*)(ws + 2211840);  // 147456
  unsigned short* uT  = (unsigned short*)(ws + 2359296);  // 147456
  unsigned short* vT  = (unsigned short*)(ws + 2506752);  // 147456
  // t2/xe2 alias E0p planes 0/1 (k_mid reads before writing; rows disjoint per block)
  float* t2  = E0p;
  float* xe2 = E0p + NN * NH;

  k_emb<<<96, 192, 0, stream>>>(x, W_emb, b_emb, W1, xinit, t1, uT, Upk);
  k_gc1<<<96, 192, 0, stream>>>(adj, t1, b1, x1, vT, Vpk);
  k_edge<<<768, 512, 0, stream>>>(adj1, uT, vT, Upk, Vpk, E0p, E1p);
  k_mid<<<96, 192, 0, stream>>>(E0p, E1p, x1, xinit, We, be, W2, We2, be2, t2, xe2);
  k_out<<<96, 256, 0, stream>>>(adj, t2, b2, xe2, W_cls, b_cls, (float*)d_out);
}